// Round 1
// baseline (683.702 us; speedup 1.0000x reference)
//
#include <hip/hip_runtime.h>

#define BB   4
#define NN   8192
#define KKK  32
#define DVV  256
#define HIDD 64

__device__ __forceinline__ float relu_(float x) { return fmaxf(x, 0.0f); }

// ---------------- Kernel 1: qe = MLP(q), one thread per (b,n) row ----------
__global__ __launch_bounds__(256) void qe_mlp_kernel(
    const float* __restrict__ qin,
    const float* __restrict__ w0, const float* __restrict__ b0,
    const float* __restrict__ w1, const float* __restrict__ b1,
    const float* __restrict__ w2, const float* __restrict__ b2,
    float* __restrict__ qe)
{
    const long row = (long)blockIdx.x * blockDim.x + threadIdx.x;   // 0..B*N-1
    const float x0 = qin[row*3+0], x1 = qin[row*3+1], x2 = qin[row*3+2];

    float a0[HIDD];
#pragma unroll
    for (int h = 0; h < HIDD; ++h)
        a0[h] = relu_(fmaf(w0[h*3+2], x2, fmaf(w0[h*3+1], x1, fmaf(w0[h*3+0], x0, b0[h]))));

    float a1[HIDD];
#pragma unroll
    for (int h = 0; h < HIDD; ++h) {
        float acc = b1[h];
#pragma unroll
        for (int i = 0; i < HIDD; ++i) acc = fmaf(w1[h*HIDD+i], a0[i], acc);
        a1[h] = relu_(acc);
    }

#pragma unroll 8
    for (int h = 0; h < HIDD; ++h) {
        float acc = b2[h];
#pragma unroll
        for (int i = 0; i < HIDD; ++i) acc = fmaf(w2[h*HIDD+i], a1[i], acc);
        qe[row*HIDD + h] = acc;
    }
}

// ------- Kernel 2: k-MLP (fused with qe-dot) + softmax + weighted v-sum ----
// One thread per k-row. 256 threads/block = 8 groups of 32.
__global__ __launch_bounds__(256) void attn_kernel(
    const float* __restrict__ kin, const float* __restrict__ v,
    const float* __restrict__ w0, const float* __restrict__ b0,
    const float* __restrict__ w1, const float* __restrict__ b1,
    const float* __restrict__ w2, const float* __restrict__ b2,
    const float* __restrict__ qe, float* __restrict__ out)
{
    const int tid = threadIdx.x;
    const int lk  = tid & 31;                              // k index within group
    const long group = (long)blockIdx.x * 8 + (tid >> 5);  // b*N + n
    const long row   = group * KKK + lk;

    const float x0 = kin[row*3+0], x1 = kin[row*3+1], x2 = kin[row*3+2];

    float a0[HIDD];
#pragma unroll
    for (int h = 0; h < HIDD; ++h)
        a0[h] = relu_(fmaf(w0[h*3+2], x2, fmaf(w0[h*3+1], x1, fmaf(w0[h*3+0], x0, b0[h]))));

    float a1[HIDD];
#pragma unroll
    for (int h = 0; h < HIDD; ++h) {
        float acc = b1[h];
#pragma unroll
        for (int i = 0; i < HIDD; ++i) acc = fmaf(w1[h*HIDD+i], a0[i], acc);
        a1[h] = relu_(acc);
    }

    // layer 2 fused with dot(qe, ke): never materialize ke
    const float* __restrict__ qeg = qe + group * HIDD;
    float logit = 0.0f;
#pragma unroll 8
    for (int h = 0; h < HIDD; ++h) {
        float acc = b2[h];
#pragma unroll
        for (int i = 0; i < HIDD; ++i) acc = fmaf(w2[h*HIDD+i], a1[i], acc);
        logit = fmaf(acc, qeg[h], logit);
    }

    // softmax over the 32 lanes of this group (scale = 1/sqrt(3): PRE-MLP dim)
    float s = logit * 0.5773502691896258f;
    float m = s;
#pragma unroll
    for (int off = 16; off > 0; off >>= 1) m = fmaxf(m, __shfl_xor(m, off, 32));
    const float e = __expf(s - m);
    float sum = e;
#pragma unroll
    for (int off = 16; off > 0; off >>= 1) sum += __shfl_xor(sum, off, 32);
    const float w = e / sum;

    // weighted sum over v: each lane owns 8 contiguous dv-columns
    const float* __restrict__ vg = v + group * (KKK * (long)DVV) + lk * 8;
    float4 acc0 = make_float4(0,0,0,0), acc1 = make_float4(0,0,0,0);
#pragma unroll 8
    for (int kk = 0; kk < KKK; ++kk) {
        const float wk = __shfl(w, kk, 32);
        const float4 va = *(const float4*)(vg + (long)kk * DVV);
        const float4 vb = *(const float4*)(vg + (long)kk * DVV + 4);
        acc0.x = fmaf(wk, va.x, acc0.x); acc0.y = fmaf(wk, va.y, acc0.y);
        acc0.z = fmaf(wk, va.z, acc0.z); acc0.w = fmaf(wk, va.w, acc0.w);
        acc1.x = fmaf(wk, vb.x, acc1.x); acc1.y = fmaf(wk, vb.y, acc1.y);
        acc1.z = fmaf(wk, vb.z, acc1.z); acc1.w = fmaf(wk, vb.w, acc1.w);
    }
    float* op = out + group * (long)DVV + lk * 8;
    *(float4*)op       = acc0;
    *(float4*)(op + 4) = acc1;
}

extern "C" void kernel_launch(void* const* d_in, const int* in_sizes, int n_in,
                              void* d_out, int out_size, void* d_ws, size_t ws_size,
                              hipStream_t stream)
{
    const float* q   = (const float*)d_in[0];
    const float* k   = (const float*)d_in[1];
    const float* v   = (const float*)d_in[2];
    const float* qw0 = (const float*)d_in[3];
    const float* qb0 = (const float*)d_in[4];
    const float* qw1 = (const float*)d_in[5];
    const float* qb1 = (const float*)d_in[6];
    const float* qw2 = (const float*)d_in[7];
    const float* qb2 = (const float*)d_in[8];
    const float* kw0 = (const float*)d_in[9];
    const float* kb0 = (const float*)d_in[10];
    const float* kw1 = (const float*)d_in[11];
    const float* kb1 = (const float*)d_in[12];
    const float* kw2 = (const float*)d_in[13];
    const float* kb2 = (const float*)d_in[14];

    float* qe  = (float*)d_ws;          // B*N*64 floats = 8 MB scratch
    float* out = (float*)d_out;

    const int BN = BB * NN;             // 32768 groups
    qe_mlp_kernel<<<BN / 256, 256, 0, stream>>>(q, qw0, qb0, qw1, qb1, qw2, qb2, qe);
    attn_kernel<<<BN / 8, 256, 0, stream>>>(k, v, kw0, kb0, kw1, kb1, kw2, kb2, qe, out);
}

// Round 2
// 239.804 us; speedup vs baseline: 2.8511x; 2.8511x over previous
//
#include <hip/hip_runtime.h>

#define HID 64

typedef __attribute__((ext_vector_type(8))) short bf16x8;
typedef __attribute__((ext_vector_type(4))) float f32x4;

__device__ __forceinline__ unsigned f2bf1(float x){
  unsigned u = __builtin_bit_cast(unsigned, x);
  return (u + 0x7FFFu + ((u >> 16) & 1u)) >> 16;
}
__device__ __forceinline__ unsigned packbf(float a, float b){
  return f2bf1(a) | (f2bf1(b) << 16);
}
// Activation tile: 256 rows x 128B (64 bf16 feats), XOR-swizzled within row.
__device__ __forceinline__ int act_addr(int r, int byteInRow){
  return r*128 + (byteInRow ^ ((r & 7) << 4));
}

#define LDS_W0 32768
#define LDS_W1 36864
#define LDS_W2 45056
#define LDS_SZ 53248

// Weights staged in exact MFMA arg0 (M-side) fragment order:
// frag value(tile ft, ks): feat = 16*ft + (l&15), k = ks*32 + 8*(l>>4) + j
__device__ __forceinline__ void stage_weights(char* lds, int t,
    const float* __restrict__ w0, const float* __restrict__ b0,
    const float* __restrict__ w1, const float* __restrict__ w2)
{
  unsigned* W0p = (unsigned*)(lds + LDS_W0);
  unsigned* W1p = (unsigned*)(lds + LDS_W1);
  unsigned* W2p = (unsigned*)(lds + LDS_W2);
#pragma unroll
  for (int u = 0; u < 4; ++u) {          // W0': 1024 uints (K=32, bias in col 3)
    int s2 = t + 256*u;
    int j2 = s2 & 3, l = (s2 >> 2) & 63, ct = s2 >> 8;
    int feat = 16*ct + (l & 15);
    int k0 = 8*(l >> 4) + 2*j2;
    float a = (k0   < 3) ? w0[feat*3 + k0]   : (k0   == 3 ? b0[feat] : 0.f);
    float b = (k0+1 < 3) ? w0[feat*3 + k0+1] : (k0+1 == 3 ? b0[feat] : 0.f);
    W0p[s2] = packbf(a, b);
  }
#pragma unroll
  for (int u = 0; u < 8; ++u) {          // W1/W2: 2048 uints each
    int s2 = t + 256*u;
    int j2 = s2 & 3, l = (s2 >> 2) & 63, ctks = s2 >> 8;
    int ct = ctks & 3, ks = ctks >> 2;
    int feat = 16*ct + (l & 15);
    int k = ks*32 + 8*(l >> 4) + 2*j2;
    W1p[s2] = packbf(w1[feat*64 + k], w1[feat*64 + k + 1]);
    W2p[s2] = packbf(w2[feat*64 + k], w2[feat*64 + k + 1]);
  }
}

// 3-layer MLP on 256 rows/block via MFMA. Result (layer2 + bias, no relu)
// left in acc2[ft][rt]: value(feat = 16*ft+4*(lane>>4)+i, row = wv*64+16*rt+(lane&15)).
__device__ __forceinline__ void mlp3(char* lds, int t,
    const float* __restrict__ xin, long rowbase,
    const float* __restrict__ w0, const float* __restrict__ b0,
    const float* __restrict__ w1, const float* __restrict__ b1,
    const float* __restrict__ w2, const float* __restrict__ b2,
    f32x4 acc2[4][4])
{
  const int lane = t & 63, wv = t >> 6;
  const int q = lane >> 4, lm = lane & 15;
  const int wbase = wv * 64;

  stage_weights(lds, t, w0, b0, w1, w2);

  { // x-stage: own row r = t, zero-padded to K=32, 1.0 in col 3 (bias trick)
    const float* xr = xin + (rowbase + t) * 3;
    float x0 = xr[0], x1 = xr[1], x2 = xr[2];
#pragma unroll
    for (int j2 = 0; j2 < 16; ++j2) {
      unsigned val = (j2 == 0) ? packbf(x0, x1) : (j2 == 1) ? packbf(x2, 1.0f) : 0u;
      *(unsigned*)(lds + act_addr(t, j2*4)) = val;
    }
  }
  __syncthreads();

  // per-lane bias fragments: b[16*ft + 4*q + i]
  float b1v[16], b2v[16];
#pragma unroll
  for (int ft = 0; ft < 4; ++ft) {
    f32x4 t1 = *(const f32x4*)(b1 + 16*ft + 4*q);
    f32x4 t2 = *(const f32x4*)(b2 + 16*ft + 4*q);
#pragma unroll
    for (int i = 0; i < 4; ++i) { b1v[4*ft+i] = t1[i]; b2v[4*ft+i] = t2[i]; }
  }

  // ---------------- layer 0 (K=32, bias folded) ----------------
  f32x4 h[4][4];
#pragma unroll
  for (int ft = 0; ft < 4; ++ft)
#pragma unroll
    for (int rt = 0; rt < 4; ++rt) h[ft][rt] = (f32x4)(0.f);

  bf16x8 a0[4];
#pragma unroll
  for (int rt = 0; rt < 4; ++rt)
    a0[rt] = *(const bf16x8*)(lds + act_addr(wbase + 16*rt + lm, 16*q));
  bf16x8 wf0[4];
#pragma unroll
  for (int ft = 0; ft < 4; ++ft)
    wf0[ft] = *(const bf16x8*)(lds + LDS_W0 + ft*1024 + lane*16);
#pragma unroll
  for (int ft = 0; ft < 4; ++ft)
#pragma unroll
    for (int rt = 0; rt < 4; ++rt)
      h[ft][rt] = __builtin_amdgcn_mfma_f32_16x16x32_bf16(wf0[ft], a0[rt], h[ft][rt], 0, 0, 0);

  // epilogue L0: relu -> bf16 -> act LDS (lane holds 4 consecutive feats of one row)
#pragma unroll
  for (int ft = 0; ft < 4; ++ft)
#pragma unroll
    for (int rt = 0; rt < 4; ++rt) {
      int rr = wbase + 16*rt + lm;
      int nb = (16*ft + 4*q) * 2;
      f32x4 vv = h[ft][rt];
      *(unsigned*)(lds + act_addr(rr, nb))     = packbf(fmaxf(vv[0],0.f), fmaxf(vv[1],0.f));
      *(unsigned*)(lds + act_addr(rr, nb + 4)) = packbf(fmaxf(vv[2],0.f), fmaxf(vv[3],0.f));
    }

  // ---------------- layer 1 (K=64) ----------------
  bf16x8 a1[4][2];
#pragma unroll
  for (int rt = 0; rt < 4; ++rt)
#pragma unroll
    for (int ks = 0; ks < 2; ++ks)
      a1[rt][ks] = *(const bf16x8*)(lds + act_addr(wbase + 16*rt + lm, 64*ks + 16*q));
  f32x4 h1[4][4];
#pragma unroll
  for (int ft = 0; ft < 4; ++ft)
#pragma unroll
    for (int rt = 0; rt < 4; ++rt) h1[ft][rt] = (f32x4)(0.f);
#pragma unroll
  for (int ks = 0; ks < 2; ++ks) {
    bf16x8 wf[4];
#pragma unroll
    for (int ft = 0; ft < 4; ++ft)
      wf[ft] = *(const bf16x8*)(lds + LDS_W1 + (ks*4 + ft)*1024 + lane*16);
#pragma unroll
    for (int ft = 0; ft < 4; ++ft)
#pragma unroll
      for (int rt = 0; rt < 4; ++rt)
        h1[ft][rt] = __builtin_amdgcn_mfma_f32_16x16x32_bf16(wf[ft], a1[rt][ks], h1[ft][rt], 0, 0, 0);
  }
#pragma unroll
  for (int ft = 0; ft < 4; ++ft)
#pragma unroll
    for (int rt = 0; rt < 4; ++rt) {
      int rr = wbase + 16*rt + lm;
      int nb = (16*ft + 4*q) * 2;
      f32x4 vv = h1[ft][rt];
      float e0 = fmaxf(vv[0] + b1v[4*ft+0], 0.f), e1 = fmaxf(vv[1] + b1v[4*ft+1], 0.f);
      float e2 = fmaxf(vv[2] + b1v[4*ft+2], 0.f), e3 = fmaxf(vv[3] + b1v[4*ft+3], 0.f);
      *(unsigned*)(lds + act_addr(rr, nb))     = packbf(e0, e1);
      *(unsigned*)(lds + act_addr(rr, nb + 4)) = packbf(e2, e3);
    }

  // ---------------- layer 2 (K=64, bias, linear) ----------------
  bf16x8 a2[4][2];
#pragma unroll
  for (int rt = 0; rt < 4; ++rt)
#pragma unroll
    for (int ks = 0; ks < 2; ++ks)
      a2[rt][ks] = *(const bf16x8*)(lds + act_addr(wbase + 16*rt + lm, 64*ks + 16*q));
#pragma unroll
  for (int ft = 0; ft < 4; ++ft)
#pragma unroll
    for (int rt = 0; rt < 4; ++rt) acc2[ft][rt] = (f32x4)(0.f);
#pragma unroll
  for (int ks = 0; ks < 2; ++ks) {
    bf16x8 wf[4];
#pragma unroll
    for (int ft = 0; ft < 4; ++ft)
      wf[ft] = *(const bf16x8*)(lds + LDS_W2 + (ks*4 + ft)*1024 + lane*16);
#pragma unroll
    for (int ft = 0; ft < 4; ++ft)
#pragma unroll
      for (int rt = 0; rt < 4; ++rt)
        acc2[ft][rt] = __builtin_amdgcn_mfma_f32_16x16x32_bf16(wf[ft], a2[rt][ks], acc2[ft][rt], 0, 0, 0);
  }
#pragma unroll
  for (int ft = 0; ft < 4; ++ft)
#pragma unroll
    for (int rt = 0; rt < 4; ++rt)
#pragma unroll
      for (int i = 0; i < 4; ++i) acc2[ft][rt][i] += b2v[4*ft+i];
}

// -------- q-path: MLP -> qe (fp32) --------
__global__ __launch_bounds__(256) void qe_mfma_kernel(
    const float* __restrict__ qin,
    const float* __restrict__ w0, const float* __restrict__ b0,
    const float* __restrict__ w1, const float* __restrict__ b1,
    const float* __restrict__ w2, const float* __restrict__ b2,
    float* __restrict__ qeout)
{
  __shared__ __align__(16) char lds[LDS_SZ];
  const int t = threadIdx.x;
  const int lane = t & 63, wv = t >> 6, q = lane >> 4, lm = lane & 15;
  const long rowbase = (long)blockIdx.x * 256;
  f32x4 acc2[4][4];
  mlp3(lds, t, qin, rowbase, w0, b0, w1, b1, w2, b2, acc2);
#pragma unroll
  for (int ft = 0; ft < 4; ++ft)
#pragma unroll
    for (int rt = 0; rt < 4; ++rt) {
      long grow = rowbase + wv*64 + 16*rt + lm;
      *(f32x4*)(qeout + grow*64 + 16*ft + 4*q) = acc2[ft][rt];
    }
}

// -------- k-path: MLP -> logits -> softmax -> weighted v-sum --------
__global__ __launch_bounds__(256) void attn_mfma_kernel(
    const float* __restrict__ kin, const float* __restrict__ v,
    const float* __restrict__ w0, const float* __restrict__ b0,
    const float* __restrict__ w1, const float* __restrict__ b1,
    const float* __restrict__ w2, const float* __restrict__ b2,
    const float* __restrict__ qe, float* __restrict__ out)
{
  __shared__ __align__(16) char lds[LDS_SZ];
  const int t = threadIdx.x;
  const int lane = t & 63, wv = t >> 6, q = lane >> 4, lm = lane & 15;
  const long rowbase = (long)blockIdx.x * 256;
  f32x4 acc2[4][4];
  mlp3(lds, t, kin, rowbase, w0, b0, w1, b1, w2, b2, acc2);

  const long Gbase = (long)blockIdx.x * 8 + wv * 2;

  // logit[row] = (ke . qe(group)) * 1/sqrt(3); partial over own 16 feats, reduce over q
  float p[4];
#pragma unroll
  for (int rt = 0; rt < 4; ++rt) {
    const float* qp = qe + (Gbase + (rt >> 1)) * 64;
    float s = 0.f;
#pragma unroll
    for (int ft = 0; ft < 4; ++ft) {
      f32x4 qv = *(const f32x4*)(qp + 16*ft + 4*q);
#pragma unroll
      for (int i = 0; i < 4; ++i) s += acc2[ft][rt][i] * qv[i];
    }
    s += __shfl_xor(s, 16, 64);
    s += __shfl_xor(s, 32, 64);
    p[rt] = s * 0.5773502691896258f;
  }

  // softmax over 32 k-rows per group (rows = 16*(rt&1) + lm across 16 lane-ids)
  float wgt[4];
#pragma unroll
  for (int g2 = 0; g2 < 2; ++g2) {
    float a = p[2*g2], b = p[2*g2+1];
    float m = fmaxf(a, b);
#pragma unroll
    for (int off = 1; off < 16; off <<= 1) m = fmaxf(m, __shfl_xor(m, off, 64));
    float ea = __expf(a - m), eb = __expf(b - m);
    float s = ea + eb;
#pragma unroll
    for (int off = 1; off < 16; off <<= 1) s += __shfl_xor(s, off, 64);
    float inv = 1.0f / s;
    wgt[2*g2] = ea * inv; wgt[2*g2+1] = eb * inv;
  }

  // v pass: lane owns 4 dv columns; v read once, fully coalesced
#pragma unroll
  for (int g2 = 0; g2 < 2; ++g2) {
    const long G = Gbase + g2;
    const f32x4* vp = (const f32x4*)(v + G * 8192) + lane;
    f32x4 acc = (f32x4)(0.f);
#pragma unroll
    for (int k = 0; k < 32; ++k) {
      float wk = __shfl(wgt[2*g2 + (k >> 4)], k & 15, 64);
      f32x4 vv = vp[k * 64];
      acc += wk * vv;
    }
    *(f32x4*)(out + G * 256 + 4*lane) = acc;
  }
}

extern "C" void kernel_launch(void* const* d_in, const int* in_sizes, int n_in,
                              void* d_out, int out_size, void* d_ws, size_t ws_size,
                              hipStream_t stream)
{
  const float* q   = (const float*)d_in[0];
  const float* k   = (const float*)d_in[1];
  const float* v   = (const float*)d_in[2];
  const float* qw0 = (const float*)d_in[3];
  const float* qb0 = (const float*)d_in[4];
  const float* qw1 = (const float*)d_in[5];
  const float* qb1 = (const float*)d_in[6];
  const float* qw2 = (const float*)d_in[7];
  const float* qb2 = (const float*)d_in[8];
  const float* kw0 = (const float*)d_in[9];
  const float* kb0 = (const float*)d_in[10];
  const float* kw1 = (const float*)d_in[11];
  const float* kb1 = (const float*)d_in[12];
  const float* kw2 = (const float*)d_in[13];
  const float* kb2 = (const float*)d_in[14];

  float* qe  = (float*)d_ws;   // 32768 * 64 floats = 8 MB
  float* out = (float*)d_out;

  qe_mfma_kernel<<<128, 256, 0, stream>>>(q, qw0, qb0, qw1, qb1, qw2, qb2, qe);
  attn_mfma_kernel<<<4096, 256, 0, stream>>>(k, v, kw0, kb0, kw1, kb1, kw2, kb2, qe, out);
}

// Round 3
// 230.400 us; speedup vs baseline: 2.9675x; 1.0408x over previous
//
#include <hip/hip_runtime.h>
#include <hip/hip_bf16.h>

typedef __attribute__((ext_vector_type(8))) short bf16x8;
typedef __attribute__((ext_vector_type(4))) float f32x4;

union BF8U { unsigned u[4]; bf16x8 v; };

__device__ __forceinline__ unsigned f2bf1(float x){
  unsigned u = __builtin_bit_cast(unsigned, x);
  return (u + 0x7FFFu + ((u >> 16) & 1u)) >> 16;
}
__device__ __forceinline__ unsigned packbf(float a, float b){
  return f2bf1(a) | (f2bf1(b) << 16);
}
__device__ __forceinline__ unsigned cvt2(float a, float b){
  return (unsigned)__bfloat16_as_ushort(__float2bfloat16(a))
       | ((unsigned)__bfloat16_as_ushort(__float2bfloat16(b)) << 16);
}

// Activation tile: 256 rows x 128B (64 bf16 feats), XOR-swizzled within row.
// Wave-private: rows [wv*64, wv*64+64) touched only by wave wv -> no barriers.
__device__ __forceinline__ int act_addr(int r, int byteInRow){
  return r*128 + (byteInRow ^ ((r & 7) << 4));
}
#define LDS_SZ 32768

// ---------- prep: pack bf16 weight fragments in exact MFMA arg0 order ------
// uint layout per path (5120 uints): W0' @0 (1024, K=32, bias in k=3),
// W1 @1024 (2048), W2 @3072 (2048). path0 = k-weights, path1 = q-weights.
__global__ __launch_bounds__(256) void prep_kernel(
    const float* __restrict__ kw0, const float* __restrict__ kb0,
    const float* __restrict__ kw1, const float* __restrict__ kw2,
    const float* __restrict__ qw0, const float* __restrict__ qb0,
    const float* __restrict__ qw1, const float* __restrict__ qw2,
    unsigned* __restrict__ WF)
{
  const int t = threadIdx.x;
  const int path = blockIdx.x;
  const float* w0 = path ? qw0 : kw0;
  const float* b0 = path ? qb0 : kb0;
  const float* w1 = path ? qw1 : kw1;
  const float* w2 = path ? qw2 : kw2;
  unsigned* out = WF + path * 5120;
#pragma unroll
  for (int u = 0; u < 4; ++u) {
    int s2 = t + 256*u;
    int j2 = s2 & 3, l = (s2 >> 2) & 63, ct = s2 >> 8;
    int feat = 16*ct + (l & 15);
    int k0 = 8*(l >> 4) + 2*j2;
    float a = (k0   < 3) ? w0[feat*3 + k0]   : (k0   == 3 ? b0[feat] : 0.f);
    float b = (k0+1 < 3) ? w0[feat*3 + k0+1] : (k0+1 == 3 ? b0[feat] : 0.f);
    out[s2] = packbf(a, b);
  }
#pragma unroll
  for (int u = 0; u < 8; ++u) {
    int s2 = t + 256*u;
    int j2 = s2 & 3, l = (s2 >> 2) & 63, ctks = s2 >> 8;
    int feat = 16*(ctks & 3) + (l & 15);
    int k = 32*(ctks >> 2) + 8*(l >> 4) + 2*j2;
    out[1024 + s2] = packbf(w1[feat*64 + k], w1[feat*64 + k + 1]);
    out[3072 + s2] = packbf(w2[feat*64 + k], w2[feat*64 + k + 1]);
  }
}

// ---------- 3-layer MLP on 256 rows/block, weights from global, no barriers
// Output acc2[ft][rt]: feat = 16*ft+4*(lane>>4)+i, row = wv*64+16*rt+(lane&15)
__device__ __forceinline__ void mlp3(char* lds, int t,
    const float* __restrict__ xin, long rowbase,
    const unsigned* __restrict__ WF,
    const float* __restrict__ b1, const float* __restrict__ b2,
    f32x4 acc2[4][4])
{
  const int lane = t & 63;
  const int q = lane >> 4, lm = lane & 15;
  const int wbase = (t >> 6) * 64;

  // x -> a0 fragments in-register (k = 8*q+j: only q==0 carries x0,x1,x2,1.0)
  bf16x8 a0[4];
#pragma unroll
  for (int rt = 0; rt < 4; ++rt) {
    const float* xr = xin + (rowbase + wbase + 16*rt + lm) * 3;
    float x0 = xr[0], x1 = xr[1], x2 = xr[2];
    BF8U u;
    u.u[0] = (q == 0) ? cvt2(x0, x1)   : 0u;
    u.u[1] = (q == 0) ? cvt2(x2, 1.0f) : 0u;
    u.u[2] = 0u; u.u[3] = 0u;
    a0[rt] = u.v;
  }

  f32x4 h[4][4];

  { // ---------------- layer 0 (K=32, bias folded into W0') ----------------
    bf16x8 wf[4];
#pragma unroll
    for (int ft = 0; ft < 4; ++ft)
      wf[ft] = *(const bf16x8*)(WF + ft*256 + lane*4);
#pragma unroll
    for (int ft = 0; ft < 4; ++ft)
#pragma unroll
      for (int rt = 0; rt < 4; ++rt) {
        h[ft][rt] = (f32x4)(0.f);
        h[ft][rt] = __builtin_amdgcn_mfma_f32_16x16x32_bf16(wf[ft], a0[rt], h[ft][rt], 0, 0, 0);
      }
#pragma unroll
    for (int ft = 0; ft < 4; ++ft)
#pragma unroll
      for (int rt = 0; rt < 4; ++rt) {
        int rr = wbase + 16*rt + lm;
        f32x4 vv = h[ft][rt];
        uint2 wp;
        wp.x = cvt2(fmaxf(vv[0],0.f), fmaxf(vv[1],0.f));
        wp.y = cvt2(fmaxf(vv[2],0.f), fmaxf(vv[3],0.f));
        *(uint2*)(lds + act_addr(rr, (16*ft + 4*q)*2)) = wp;
      }
  }

  { // ---------------- layer 1 (K=64, bias, relu) ----------------
    bf16x8 a1[4][2];
#pragma unroll
    for (int rt = 0; rt < 4; ++rt)
#pragma unroll
      for (int ks = 0; ks < 2; ++ks)
        a1[rt][ks] = *(const bf16x8*)(lds + act_addr(wbase + 16*rt + lm, 64*ks + 16*q));
    bf16x8 wf[8];
#pragma unroll
    for (int c = 0; c < 8; ++c)
      wf[c] = *(const bf16x8*)(WF + 1024 + c*256 + lane*4);
#pragma unroll
    for (int ft = 0; ft < 4; ++ft)
#pragma unroll
      for (int rt = 0; rt < 4; ++rt) {
        h[ft][rt] = (f32x4)(0.f);
        h[ft][rt] = __builtin_amdgcn_mfma_f32_16x16x32_bf16(wf[ft],   a1[rt][0], h[ft][rt], 0, 0, 0);
        h[ft][rt] = __builtin_amdgcn_mfma_f32_16x16x32_bf16(wf[4+ft], a1[rt][1], h[ft][rt], 0, 0, 0);
      }
    f32x4 b1f[4];
#pragma unroll
    for (int ft = 0; ft < 4; ++ft) b1f[ft] = *(const f32x4*)(b1 + 16*ft + 4*q);
#pragma unroll
    for (int ft = 0; ft < 4; ++ft)
#pragma unroll
      for (int rt = 0; rt < 4; ++rt) {
        int rr = wbase + 16*rt + lm;
        f32x4 vv = h[ft][rt];
        uint2 wp;
        wp.x = cvt2(fmaxf(vv[0]+b1f[ft][0],0.f), fmaxf(vv[1]+b1f[ft][1],0.f));
        wp.y = cvt2(fmaxf(vv[2]+b1f[ft][2],0.f), fmaxf(vv[3]+b1f[ft][3],0.f));
        *(uint2*)(lds + act_addr(rr, (16*ft + 4*q)*2)) = wp;
      }
  }

  { // ---------------- layer 2 (K=64, bias, linear) ----------------
    bf16x8 a2[4][2];
#pragma unroll
    for (int rt = 0; rt < 4; ++rt)
#pragma unroll
      for (int ks = 0; ks < 2; ++ks)
        a2[rt][ks] = *(const bf16x8*)(lds + act_addr(wbase + 16*rt + lm, 64*ks + 16*q));
    bf16x8 wf[8];
#pragma unroll
    for (int c = 0; c < 8; ++c)
      wf[c] = *(const bf16x8*)(WF + 3072 + c*256 + lane*4);
#pragma unroll
    for (int ft = 0; ft < 4; ++ft)
#pragma unroll
      for (int rt = 0; rt < 4; ++rt) {
        acc2[ft][rt] = (f32x4)(0.f);
        acc2[ft][rt] = __builtin_amdgcn_mfma_f32_16x16x32_bf16(wf[ft],   a2[rt][0], acc2[ft][rt], 0, 0, 0);
        acc2[ft][rt] = __builtin_amdgcn_mfma_f32_16x16x32_bf16(wf[4+ft], a2[rt][1], acc2[ft][rt], 0, 0, 0);
      }
    f32x4 b2f[4];
#pragma unroll
    for (int ft = 0; ft < 4; ++ft) b2f[ft] = *(const f32x4*)(b2 + 16*ft + 4*q);
#pragma unroll
    for (int ft = 0; ft < 4; ++ft)
#pragma unroll
      for (int rt = 0; rt < 4; ++rt)
#pragma unroll
        for (int i = 0; i < 4; ++i) acc2[ft][rt][i] += b2f[ft][i];
  }
}

// -------- q-path: MLP -> qe (fp32) --------
__global__ __launch_bounds__(256, 2) void qe_mfma_kernel(
    const float* __restrict__ qin, const unsigned* __restrict__ WF,
    const float* __restrict__ b1, const float* __restrict__ b2,
    float* __restrict__ qeout)
{
  __shared__ __align__(16) char lds[LDS_SZ];
  const int t = threadIdx.x;
  const int lane = t & 63, wv = t >> 6, q = lane >> 4, lm = lane & 15;
  const long rowbase = (long)blockIdx.x * 256;
  f32x4 acc2[4][4];
  mlp3(lds, t, qin, rowbase, WF, b1, b2, acc2);
#pragma unroll
  for (int ft = 0; ft < 4; ++ft)
#pragma unroll
    for (int rt = 0; rt < 4; ++rt) {
      long grow = rowbase + wv*64 + 16*rt + lm;
      *(f32x4*)(qeout + grow*64 + 16*ft + 4*q) = acc2[ft][rt];
    }
}

// -------- k-path: MLP -> logits -> softmax -> weighted v-sum --------
__global__ __launch_bounds__(256, 2) void attn_mfma_kernel(
    const float* __restrict__ kin, const float* __restrict__ v,
    const unsigned* __restrict__ WF,
    const float* __restrict__ b1, const float* __restrict__ b2,
    const float* __restrict__ qe, float* __restrict__ out)
{
  __shared__ __align__(16) char lds[LDS_SZ];
  const int t = threadIdx.x;
  const int lane = t & 63, wv = t >> 6, q = lane >> 4, lm = lane & 15;
  const long rowbase = (long)blockIdx.x * 256;
  f32x4 acc2[4][4];
  mlp3(lds, t, kin, rowbase, WF, b1, b2, acc2);

  const long Gbase = (long)blockIdx.x * 8 + wv * 2;

  // logit[row] = (ke . qe(group)) / sqrt(3); partial over own 16 feats, reduce over q
  float p[4];
#pragma unroll
  for (int rt = 0; rt < 4; ++rt) {
    const float* qp = qe + (Gbase + (rt >> 1)) * 64;
    float s = 0.f;
#pragma unroll
    for (int ft = 0; ft < 4; ++ft) {
      f32x4 qv = *(const f32x4*)(qp + 16*ft + 4*q);
#pragma unroll
      for (int i = 0; i < 4; ++i) s += acc2[ft][rt][i] * qv[i];
    }
    s += __shfl_xor(s, 16, 64);
    s += __shfl_xor(s, 32, 64);
    p[rt] = s * 0.5773502691896258f;
  }

  // softmax over 32 k-rows per group (row = 16*(rt&1)+lm across 16 lane-ids)
  float wgt[4];
#pragma unroll
  for (int g2 = 0; g2 < 2; ++g2) {
    float a = p[2*g2], b = p[2*g2+1];
    float m = fmaxf(a, b);
#pragma unroll
    for (int off = 1; off < 16; off <<= 1) m = fmaxf(m, __shfl_xor(m, off, 64));
    float ea = __expf(a - m), eb = __expf(b - m);
    float s = ea + eb;
#pragma unroll
    for (int off = 1; off < 16; off <<= 1) s += __shfl_xor(s, off, 64);
    float inv = 1.0f / s;
    wgt[2*g2] = ea * inv; wgt[2*g2+1] = eb * inv;
  }

  // v pass: lane owns 4 dv columns; v read once, fully coalesced
#pragma unroll
  for (int g2 = 0; g2 < 2; ++g2) {
    const long G = Gbase + g2;
    const f32x4* vp = (const f32x4*)(v + G * 8192) + lane;
    f32x4 acc = (f32x4)(0.f);
#pragma unroll
    for (int k = 0; k < 32; ++k) {
      float wk = __shfl(wgt[2*g2 + (k >> 4)], k & 15, 64);
      f32x4 vv = vp[k * 64];
      acc += wk * vv;
    }
    *(f32x4*)(out + G * 256 + 4*lane) = acc;
  }
}

extern "C" void kernel_launch(void* const* d_in, const int* in_sizes, int n_in,
                              void* d_out, int out_size, void* d_ws, size_t ws_size,
                              hipStream_t stream)
{
  const float* q   = (const float*)d_in[0];
  const float* k   = (const float*)d_in[1];
  const float* v   = (const float*)d_in[2];
  const float* qw0 = (const float*)d_in[3];
  const float* qb0 = (const float*)d_in[4];
  const float* qw1 = (const float*)d_in[5];
  const float* qb1 = (const float*)d_in[6];
  const float* qw2 = (const float*)d_in[7];
  const float* qb2 = (const float*)d_in[8];
  const float* kw0 = (const float*)d_in[9];
  const float* kb0 = (const float*)d_in[10];
  const float* kw1 = (const float*)d_in[11];
  const float* kb1 = (const float*)d_in[12];
  const float* kw2 = (const float*)d_in[13];
  const float* kb2 = (const float*)d_in[14];

  float*    qe = (float*)d_ws;                          // 8 MB
  unsigned* WF = (unsigned*)((char*)d_ws + (8u << 20)); // 40 KB fragments

  prep_kernel<<<2, 256, 0, stream>>>(kw0, kb0, kw1, kw2, qw0, qb0, qw1, qw2, WF);
  qe_mfma_kernel<<<128, 256, 0, stream>>>(q, WF + 5120, qb1, qb2, qe);
  attn_mfma_kernel<<<4096, 256, 0, stream>>>(k, v, WF, kb1, kb2, qe, (float*)d_out);
}

// Round 4
// 224.122 us; speedup vs baseline: 3.0506x; 1.0280x over previous
//
#include <hip/hip_runtime.h>
#include <hip/hip_bf16.h>

typedef __attribute__((ext_vector_type(8))) short bf16x8;
typedef __attribute__((ext_vector_type(4))) float f32x4;

union BF8U { unsigned u[4]; bf16x8 v; };

__device__ __forceinline__ unsigned f2bf1(float x){
  unsigned u = __builtin_bit_cast(unsigned, x);
  return (u + 0x7FFFu + ((u >> 16) & 1u)) >> 16;
}
__device__ __forceinline__ unsigned packbf(float a, float b){
  return f2bf1(a) | (f2bf1(b) << 16);
}
__device__ __forceinline__ unsigned cvt2(float a, float b){
  return (unsigned)__bfloat16_as_ushort(__float2bfloat16(a))
       | ((unsigned)__bfloat16_as_ushort(__float2bfloat16(b)) << 16);
}

// Activation tile: 128 rows x 128B (64 bf16 feats), XOR-swizzled within row.
// Wave-private: rows [wv*32, wv*32+32) touched only by wave wv -> no barriers.
__device__ __forceinline__ int act_addr(int r, int byteInRow){
  return r*128 + (byteInRow ^ ((r & 7) << 4));
}
#define LDS_SZ 16384

// ---------- prep: pack bf16 weight fragments in exact MFMA arg0 order ------
// uint layout per path (5120 uints): W0' @0 (1024, K=32, bias in k=3),
// W1 @1024 (2048), W2 @3072 (2048). path0 = k-weights, path1 = q-weights.
__global__ __launch_bounds__(256) void prep_kernel(
    const float* __restrict__ kw0, const float* __restrict__ kb0,
    const float* __restrict__ kw1, const float* __restrict__ kw2,
    const float* __restrict__ qw0, const float* __restrict__ qb0,
    const float* __restrict__ qw1, const float* __restrict__ qw2,
    unsigned* __restrict__ WF)
{
  const int t = threadIdx.x;
  const int path = blockIdx.x;
  const float* w0 = path ? qw0 : kw0;
  const float* b0 = path ? qb0 : kb0;
  const float* w1 = path ? qw1 : kw1;
  const float* w2 = path ? qw2 : kw2;
  unsigned* out = WF + path * 5120;
#pragma unroll
  for (int u = 0; u < 4; ++u) {
    int s2 = t + 256*u;
    int j2 = s2 & 3, l = (s2 >> 2) & 63, ct = s2 >> 8;
    int feat = 16*ct + (l & 15);
    int k0 = 8*(l >> 4) + 2*j2;
    float a = (k0   < 3) ? w0[feat*3 + k0]   : (k0   == 3 ? b0[feat] : 0.f);
    float b = (k0+1 < 3) ? w0[feat*3 + k0+1] : (k0+1 == 3 ? b0[feat] : 0.f);
    out[s2] = packbf(a, b);
  }
#pragma unroll
  for (int u = 0; u < 8; ++u) {
    int s2 = t + 256*u;
    int j2 = s2 & 3, l = (s2 >> 2) & 63, ctks = s2 >> 8;
    int feat = 16*(ctks & 3) + (l & 15);
    int k = 32*(ctks >> 2) + 8*(l >> 4) + 2*j2;
    out[1024 + s2] = packbf(w1[feat*64 + k], w1[feat*64 + k + 1]);
    out[3072 + s2] = packbf(w2[feat*64 + k], w2[feat*64 + k + 1]);
  }
}

// ---------- 3-layer MLP on 128 rows/block (32 rows/wave), no barriers ------
// Output acc2[ft][rt]: feat = 16*ft+4*(lane>>4)+i, row = wv*32+16*rt+(lane&15)
__device__ __forceinline__ void mlp3(char* lds, int t,
    const float* __restrict__ xin, long rowbase,
    const unsigned* __restrict__ WF,
    const float* __restrict__ b1, const float* __restrict__ b2,
    f32x4 acc2[4][2])
{
  const int lane = t & 63;
  const int q = lane >> 4, lm = lane & 15;
  const int wbase = (t >> 6) * 32;

  // x -> a0 fragments in-register (k = 8*q+j: only q==0 carries x0,x1,x2,1.0)
  bf16x8 a0[2];
#pragma unroll
  for (int rt = 0; rt < 2; ++rt) {
    const float* xr = xin + (rowbase + wbase + 16*rt + lm) * 3;
    float x0 = xr[0], x1 = xr[1], x2 = xr[2];
    BF8U u;
    u.u[0] = (q == 0) ? cvt2(x0, x1)   : 0u;
    u.u[1] = (q == 0) ? cvt2(x2, 1.0f) : 0u;
    u.u[2] = 0u; u.u[3] = 0u;
    a0[rt] = u.v;
  }

  f32x4 h[4][2];

  { // ---------------- layer 0 (K=32, bias folded into W0') ----------------
    bf16x8 wf[4];
#pragma unroll
    for (int ft = 0; ft < 4; ++ft)
      wf[ft] = *(const bf16x8*)(WF + ft*256 + lane*4);
#pragma unroll
    for (int ft = 0; ft < 4; ++ft)
#pragma unroll
      for (int rt = 0; rt < 2; ++rt) {
        h[ft][rt] = (f32x4)(0.f);
        h[ft][rt] = __builtin_amdgcn_mfma_f32_16x16x32_bf16(wf[ft], a0[rt], h[ft][rt], 0, 0, 0);
      }
#pragma unroll
    for (int ft = 0; ft < 4; ++ft)
#pragma unroll
      for (int rt = 0; rt < 2; ++rt) {
        int rr = wbase + 16*rt + lm;
        f32x4 vv = h[ft][rt];
        uint2 wp;
        wp.x = cvt2(fmaxf(vv[0],0.f), fmaxf(vv[1],0.f));
        wp.y = cvt2(fmaxf(vv[2],0.f), fmaxf(vv[3],0.f));
        *(uint2*)(lds + act_addr(rr, (16*ft + 4*q)*2)) = wp;
      }
  }

  { // ---------------- layer 1 (K=64, bias, relu) ----------------
    bf16x8 a1[2][2];
#pragma unroll
    for (int rt = 0; rt < 2; ++rt)
#pragma unroll
      for (int ks = 0; ks < 2; ++ks)
        a1[rt][ks] = *(const bf16x8*)(lds + act_addr(wbase + 16*rt + lm, 64*ks + 16*q));
    bf16x8 wf[8];
#pragma unroll
    for (int c = 0; c < 8; ++c)
      wf[c] = *(const bf16x8*)(WF + 1024 + c*256 + lane*4);
#pragma unroll
    for (int ft = 0; ft < 4; ++ft)
#pragma unroll
      for (int rt = 0; rt < 2; ++rt) {
        h[ft][rt] = (f32x4)(0.f);
        h[ft][rt] = __builtin_amdgcn_mfma_f32_16x16x32_bf16(wf[ft],   a1[rt][0], h[ft][rt], 0, 0, 0);
        h[ft][rt] = __builtin_amdgcn_mfma_f32_16x16x32_bf16(wf[4+ft], a1[rt][1], h[ft][rt], 0, 0, 0);
      }
#pragma unroll
    for (int ft = 0; ft < 4; ++ft) {
      f32x4 b1f = *(const f32x4*)(b1 + 16*ft + 4*q);
#pragma unroll
      for (int rt = 0; rt < 2; ++rt) {
        int rr = wbase + 16*rt + lm;
        f32x4 vv = h[ft][rt];
        uint2 wp;
        wp.x = cvt2(fmaxf(vv[0]+b1f[0],0.f), fmaxf(vv[1]+b1f[1],0.f));
        wp.y = cvt2(fmaxf(vv[2]+b1f[2],0.f), fmaxf(vv[3]+b1f[3],0.f));
        *(uint2*)(lds + act_addr(rr, (16*ft + 4*q)*2)) = wp;
      }
    }
  }

  { // ---------------- layer 2 (K=64, bias, linear) ----------------
    bf16x8 a2[2][2];
#pragma unroll
    for (int rt = 0; rt < 2; ++rt)
#pragma unroll
      for (int ks = 0; ks < 2; ++ks)
        a2[rt][ks] = *(const bf16x8*)(lds + act_addr(wbase + 16*rt + lm, 64*ks + 16*q));
    bf16x8 wf[8];
#pragma unroll
    for (int c = 0; c < 8; ++c)
      wf[c] = *(const bf16x8*)(WF + 3072 + c*256 + lane*4);
#pragma unroll
    for (int ft = 0; ft < 4; ++ft)
#pragma unroll
      for (int rt = 0; rt < 2; ++rt) {
        acc2[ft][rt] = (f32x4)(0.f);
        acc2[ft][rt] = __builtin_amdgcn_mfma_f32_16x16x32_bf16(wf[ft],   a2[rt][0], acc2[ft][rt], 0, 0, 0);
        acc2[ft][rt] = __builtin_amdgcn_mfma_f32_16x16x32_bf16(wf[4+ft], a2[rt][1], acc2[ft][rt], 0, 0, 0);
      }
#pragma unroll
    for (int ft = 0; ft < 4; ++ft) {
      f32x4 b2f = *(const f32x4*)(b2 + 16*ft + 4*q);
#pragma unroll
      for (int rt = 0; rt < 2; ++rt)
#pragma unroll
        for (int i = 0; i < 4; ++i) acc2[ft][rt][i] += b2f[i];
    }
  }
}

// -------- q-path: MLP -> qe (fp32) --------
__global__ __launch_bounds__(256, 3) void qe_mfma_kernel(
    const float* __restrict__ qin, const unsigned* __restrict__ WF,
    const float* __restrict__ b1, const float* __restrict__ b2,
    float* __restrict__ qeout)
{
  __shared__ __align__(16) char lds[LDS_SZ];
  const int t = threadIdx.x;
  const int lane = t & 63, wv = t >> 6, q = lane >> 4, lm = lane & 15;
  const long rowbase = (long)blockIdx.x * 128;
  f32x4 acc2[4][2];
  mlp3(lds, t, qin, rowbase, WF, b1, b2, acc2);
#pragma unroll
  for (int ft = 0; ft < 4; ++ft)
#pragma unroll
    for (int rt = 0; rt < 2; ++rt) {
      long grow = rowbase + wv*32 + 16*rt + lm;
      *(f32x4*)(qeout + grow*64 + 16*ft + 4*q) = acc2[ft][rt];
    }
}

// -------- k-path: MLP -> logits -> softmax -> weighted v-sum --------
// One wave owns exactly one group (32 k-rows).
__global__ __launch_bounds__(256, 3) void attn_mfma_kernel(
    const float* __restrict__ kin, const float* __restrict__ v,
    const unsigned* __restrict__ WF,
    const float* __restrict__ b1, const float* __restrict__ b2,
    const float* __restrict__ qe, float* __restrict__ out)
{
  __shared__ __align__(16) char lds[LDS_SZ];
  const int t = threadIdx.x;
  const int lane = t & 63, wv = t >> 6, q = lane >> 4, lm = lane & 15;
  const long rowbase = (long)blockIdx.x * 128;
  f32x4 acc2[4][2];
  mlp3(lds, t, kin, rowbase, WF, b1, b2, acc2);

  const long G = (long)blockIdx.x * 4 + wv;   // this wave's group

  // logit[row] = (ke . qe(G)) / sqrt(3); partial over own 16 feats, reduce over q
  const float* qp = qe + G * 64;
  float p[2];
#pragma unroll
  for (int rt = 0; rt < 2; ++rt) {
    float s = 0.f;
#pragma unroll
    for (int ft = 0; ft < 4; ++ft) {
      f32x4 qv = *(const f32x4*)(qp + 16*ft + 4*q);
#pragma unroll
      for (int i = 0; i < 4; ++i) s += acc2[ft][rt][i] * qv[i];
    }
    s += __shfl_xor(s, 16, 64);
    s += __shfl_xor(s, 32, 64);
    p[rt] = s * 0.5773502691896258f;
  }

  // softmax over the 32 rows (row = 16*rt + lm, replicated across q)
  float m = fmaxf(p[0], p[1]);
#pragma unroll
  for (int off = 1; off < 16; off <<= 1) m = fmaxf(m, __shfl_xor(m, off, 64));
  float e0 = __expf(p[0] - m), e1 = __expf(p[1] - m);
  float s = e0 + e1;
#pragma unroll
  for (int off = 1; off < 16; off <<= 1) s += __shfl_xor(s, off, 64);
  const float inv = 1.0f / s;
  float wgt[2] = { e0 * inv, e1 * inv };

  // v pass: lane owns 4 dv columns of group G; v read once, fully coalesced
  const f32x4* vp = (const f32x4*)(v + G * 8192) + lane;
  f32x4 acc = (f32x4)(0.f);
#pragma unroll
  for (int k = 0; k < 32; ++k) {
    float wk = __shfl(wgt[k >> 4], k & 15, 64);
    f32x4 vv = vp[k * 64];
    acc += wk * vv;
  }
  *(f32x4*)(out + G * 256 + 4*lane) = acc;
}

extern "C" void kernel_launch(void* const* d_in, const int* in_sizes, int n_in,
                              void* d_out, int out_size, void* d_ws, size_t ws_size,
                              hipStream_t stream)
{
  const float* q   = (const float*)d_in[0];
  const float* k   = (const float*)d_in[1];
  const float* v   = (const float*)d_in[2];
  const float* qw0 = (const float*)d_in[3];
  const float* qb0 = (const float*)d_in[4];
  const float* qw1 = (const float*)d_in[5];
  const float* qb1 = (const float*)d_in[6];
  const float* qw2 = (const float*)d_in[7];
  const float* qb2 = (const float*)d_in[8];
  const float* kw0 = (const float*)d_in[9];
  const float* kb0 = (const float*)d_in[10];
  const float* kw1 = (const float*)d_in[11];
  const float* kb1 = (const float*)d_in[12];
  const float* kw2 = (const float*)d_in[13];
  const float* kb2 = (const float*)d_in[14];

  float*    qe = (float*)d_ws;                          // 8 MB
  unsigned* WF = (unsigned*)((char*)d_ws + (8u << 20)); // 40 KB fragments

  prep_kernel<<<2, 256, 0, stream>>>(kw0, kb0, kw1, kw2, qw0, qb0, qw1, qw2, WF);
  qe_mfma_kernel<<<256, 256, 0, stream>>>(q, WF + 5120, qb1, qb2, qe);
  attn_mfma_kernel<<<8192, 256, 0, stream>>>(k, v, WF, kb1, kb2, qe, (float*)d_out);
}

// Round 5
// 221.739 us; speedup vs baseline: 3.0834x; 1.0107x over previous
//
#include <hip/hip_runtime.h>
#include <hip/hip_bf16.h>

typedef __attribute__((ext_vector_type(8))) short bf16x8;
typedef __attribute__((ext_vector_type(4))) float f32x4;

union BF8U { unsigned u[4]; bf16x8 v; };

#define PF 8   // v-slices prefetched per wave during the MLP (32 VGPR)

__device__ __forceinline__ unsigned f2bf1(float x){
  unsigned u = __builtin_bit_cast(unsigned, x);
  return (u + 0x7FFFu + ((u >> 16) & 1u)) >> 16;
}
__device__ __forceinline__ unsigned packbf(float a, float b){
  return f2bf1(a) | (f2bf1(b) << 16);
}
__device__ __forceinline__ unsigned cvt2(float a, float b){
  return (unsigned)__bfloat16_as_ushort(__float2bfloat16(a))
       | ((unsigned)__bfloat16_as_ushort(__float2bfloat16(b)) << 16);
}

// Activation tile: 128 rows x 128B (64 bf16 feats), XOR-swizzled within row.
// Wave-private: rows [wv*32, wv*32+32) touched only by wave wv -> no barriers.
__device__ __forceinline__ int act_addr(int r, int byteInRow){
  return r*128 + (byteInRow ^ ((r & 7) << 4));
}
#define LDS_SZ 16384

// ---------- prep: pack bf16 weight fragments in exact MFMA arg0 order ------
__global__ __launch_bounds__(256) void prep_kernel(
    const float* __restrict__ kw0, const float* __restrict__ kb0,
    const float* __restrict__ kw1, const float* __restrict__ kw2,
    const float* __restrict__ qw0, const float* __restrict__ qb0,
    const float* __restrict__ qw1, const float* __restrict__ qw2,
    unsigned* __restrict__ WF)
{
  const int t = threadIdx.x;
  const int path = blockIdx.x;
  const float* w0 = path ? qw0 : kw0;
  const float* b0 = path ? qb0 : kb0;
  const float* w1 = path ? qw1 : kw1;
  const float* w2 = path ? qw2 : kw2;
  unsigned* out = WF + path * 5120;
#pragma unroll
  for (int u = 0; u < 4; ++u) {
    int s2 = t + 256*u;
    int j2 = s2 & 3, l = (s2 >> 2) & 63, ct = s2 >> 8;
    int feat = 16*ct + (l & 15);
    int k0 = 8*(l >> 4) + 2*j2;
    float a = (k0   < 3) ? w0[feat*3 + k0]   : (k0   == 3 ? b0[feat] : 0.f);
    float b = (k0+1 < 3) ? w0[feat*3 + k0+1] : (k0+1 == 3 ? b0[feat] : 0.f);
    out[s2] = packbf(a, b);
  }
#pragma unroll
  for (int u = 0; u < 8; ++u) {
    int s2 = t + 256*u;
    int j2 = s2 & 3, l = (s2 >> 2) & 63, ctks = s2 >> 8;
    int feat = 16*(ctks & 3) + (l & 15);
    int k = 32*(ctks >> 2) + 8*(l >> 4) + 2*j2;
    out[1024 + s2] = packbf(w1[feat*64 + k], w1[feat*64 + k + 1]);
    out[3072 + s2] = packbf(w2[feat*64 + k], w2[feat*64 + k + 1]);
  }
}

// ---------- 3-layer MLP on 32 rows/wave from pre-loaded x, no barriers -----
// Output acc2[ft][rt]: feat = 16*ft+4*(lane>>4)+i, row = wv*32+16*rt+(lane&15)
__device__ __forceinline__ void mlp3(char* lds, int t,
    const float xv[2][3],
    const unsigned* __restrict__ WF,
    const float* __restrict__ b1, const float* __restrict__ b2,
    f32x4 acc2[4][2])
{
  const int lane = t & 63;
  const int q = lane >> 4, lm = lane & 15;
  const int wbase = (t >> 6) * 32;

  // x -> a0 fragments in-register (k = 8*q+j: only q==0 carries x0,x1,x2,1.0)
  bf16x8 a0[2];
#pragma unroll
  for (int rt = 0; rt < 2; ++rt) {
    BF8U u;
    u.u[0] = (q == 0) ? cvt2(xv[rt][0], xv[rt][1]) : 0u;
    u.u[1] = (q == 0) ? cvt2(xv[rt][2], 1.0f)      : 0u;
    u.u[2] = 0u; u.u[3] = 0u;
    a0[rt] = u.v;
  }

  f32x4 h[4][2];

  { // ---------------- layer 0 (K=32, bias folded into W0') ----------------
    bf16x8 wf[4];
#pragma unroll
    for (int ft = 0; ft < 4; ++ft)
      wf[ft] = *(const bf16x8*)(WF + ft*256 + lane*4);
#pragma unroll
    for (int ft = 0; ft < 4; ++ft)
#pragma unroll
      for (int rt = 0; rt < 2; ++rt) {
        h[ft][rt] = (f32x4)(0.f);
        h[ft][rt] = __builtin_amdgcn_mfma_f32_16x16x32_bf16(wf[ft], a0[rt], h[ft][rt], 0, 0, 0);
      }
#pragma unroll
    for (int ft = 0; ft < 4; ++ft)
#pragma unroll
      for (int rt = 0; rt < 2; ++rt) {
        int rr = wbase + 16*rt + lm;
        f32x4 vv = h[ft][rt];
        uint2 wp;
        wp.x = cvt2(fmaxf(vv[0],0.f), fmaxf(vv[1],0.f));
        wp.y = cvt2(fmaxf(vv[2],0.f), fmaxf(vv[3],0.f));
        *(uint2*)(lds + act_addr(rr, (16*ft + 4*q)*2)) = wp;
      }
  }

  { // ---------------- layer 1 (K=64, bias, relu) ----------------
    bf16x8 a1[2][2];
#pragma unroll
    for (int rt = 0; rt < 2; ++rt)
#pragma unroll
      for (int ks = 0; ks < 2; ++ks)
        a1[rt][ks] = *(const bf16x8*)(lds + act_addr(wbase + 16*rt + lm, 64*ks + 16*q));
    bf16x8 wf[8];
#pragma unroll
    for (int c = 0; c < 8; ++c)
      wf[c] = *(const bf16x8*)(WF + 1024 + c*256 + lane*4);
#pragma unroll
    for (int ft = 0; ft < 4; ++ft)
#pragma unroll
      for (int rt = 0; rt < 2; ++rt) {
        h[ft][rt] = (f32x4)(0.f);
        h[ft][rt] = __builtin_amdgcn_mfma_f32_16x16x32_bf16(wf[ft],   a1[rt][0], h[ft][rt], 0, 0, 0);
        h[ft][rt] = __builtin_amdgcn_mfma_f32_16x16x32_bf16(wf[4+ft], a1[rt][1], h[ft][rt], 0, 0, 0);
      }
#pragma unroll
    for (int ft = 0; ft < 4; ++ft) {
      f32x4 b1f = *(const f32x4*)(b1 + 16*ft + 4*q);
#pragma unroll
      for (int rt = 0; rt < 2; ++rt) {
        int rr = wbase + 16*rt + lm;
        f32x4 vv = h[ft][rt];
        uint2 wp;
        wp.x = cvt2(fmaxf(vv[0]+b1f[0],0.f), fmaxf(vv[1]+b1f[1],0.f));
        wp.y = cvt2(fmaxf(vv[2]+b1f[2],0.f), fmaxf(vv[3]+b1f[3],0.f));
        *(uint2*)(lds + act_addr(rr, (16*ft + 4*q)*2)) = wp;
      }
    }
  }

  { // ---------------- layer 2 (K=64, bias, linear) ----------------
    bf16x8 a2[2][2];
#pragma unroll
    for (int rt = 0; rt < 2; ++rt)
#pragma unroll
      for (int ks = 0; ks < 2; ++ks)
        a2[rt][ks] = *(const bf16x8*)(lds + act_addr(wbase + 16*rt + lm, 64*ks + 16*q));
    bf16x8 wf[8];
#pragma unroll
    for (int c = 0; c < 8; ++c)
      wf[c] = *(const bf16x8*)(WF + 3072 + c*256 + lane*4);
#pragma unroll
    for (int ft = 0; ft < 4; ++ft)
#pragma unroll
      for (int rt = 0; rt < 2; ++rt) {
        acc2[ft][rt] = (f32x4)(0.f);
        acc2[ft][rt] = __builtin_amdgcn_mfma_f32_16x16x32_bf16(wf[ft],   a2[rt][0], acc2[ft][rt], 0, 0, 0);
        acc2[ft][rt] = __builtin_amdgcn_mfma_f32_16x16x32_bf16(wf[4+ft], a2[rt][1], acc2[ft][rt], 0, 0, 0);
      }
#pragma unroll
    for (int ft = 0; ft < 4; ++ft) {
      f32x4 b2f = *(const f32x4*)(b2 + 16*ft + 4*q);
#pragma unroll
      for (int rt = 0; rt < 2; ++rt)
#pragma unroll
        for (int i = 0; i < 4; ++i) acc2[ft][rt][i] += b2f[i];
    }
  }
}

// -------- q-path: MLP -> qe (fp32) --------
__global__ __launch_bounds__(256, 3) void qe_mfma_kernel(
    const float* __restrict__ qin, const unsigned* __restrict__ WF,
    const float* __restrict__ b1, const float* __restrict__ b2,
    float* __restrict__ qeout)
{
  __shared__ __align__(16) char lds[LDS_SZ];
  const int t = threadIdx.x;
  const int lane = t & 63, wv = t >> 6, q = lane >> 4, lm = lane & 15;
  const long rowbase = (long)blockIdx.x * 128;
  const int wbase = wv * 32;
  float xv[2][3];
#pragma unroll
  for (int rt = 0; rt < 2; ++rt) {
    const float* xr = qin + (rowbase + wbase + 16*rt + lm) * 3;
    xv[rt][0] = xr[0]; xv[rt][1] = xr[1]; xv[rt][2] = xr[2];
  }
  f32x4 acc2[4][2];
  mlp3(lds, t, xv, WF, b1, b2, acc2);
#pragma unroll
  for (int ft = 0; ft < 4; ++ft)
#pragma unroll
    for (int rt = 0; rt < 2; ++rt) {
      long grow = rowbase + wbase + 16*rt + lm;
      *(f32x4*)(qeout + grow*64 + 16*ft + 4*q) = acc2[ft][rt];
    }
}

// -------- k-path: MLP -> logits -> softmax -> weighted v-sum --------
// One wave owns exactly one group (32 k-rows). v prefetched under the MLP.
__global__ __launch_bounds__(256, 3) void attn_mfma_kernel(
    const float* __restrict__ kin, const float* __restrict__ v,
    const unsigned* __restrict__ WF,
    const float* __restrict__ b1, const float* __restrict__ b2,
    const float* __restrict__ qe, float* __restrict__ out)
{
  __shared__ __align__(16) char lds[LDS_SZ];
  const int t = threadIdx.x;
  const int lane = t & 63, wv = t >> 6, q = lane >> 4, lm = lane & 15;
  const long rowbase = (long)blockIdx.x * 128;
  const int wbase = wv * 32;
  const long G = (long)blockIdx.x * 4 + wv;   // this wave's group

  // (1) k-row loads first (oldest in VMEM FIFO -> MLP start waits only these)
  float xv[2][3];
#pragma unroll
  for (int rt = 0; rt < 2; ++rt) {
    const float* xr = kin + (rowbase + wbase + 16*rt + lm) * 3;
    xv[rt][0] = xr[0]; xv[rt][1] = xr[1]; xv[rt][2] = xr[2];
  }
  __builtin_amdgcn_sched_barrier(0);

  // (2) v-prefetch: PF slices issued now, consumed after softmax. Keeps HBM
  // busy during the (VMEM-silent) MLP phase. Addresses independent of MLP.
  const f32x4* vp = (const f32x4*)(v + G * 8192) + lane;
  f32x4 pre[PF];
#pragma unroll
  for (int s = 0; s < PF; ++s) pre[s] = vp[s * 64];
  __builtin_amdgcn_sched_barrier(0);

  f32x4 acc2[4][2];
  mlp3(lds, t, xv, WF, b1, b2, acc2);

  // logit[row] = (ke . qe(G)) / sqrt(3); partial over own 16 feats, reduce over q
  const float* qp = qe + G * 64;
  float p[2];
#pragma unroll
  for (int rt = 0; rt < 2; ++rt) {
    float s = 0.f;
#pragma unroll
    for (int ft = 0; ft < 4; ++ft) {
      f32x4 qv = *(const f32x4*)(qp + 16*ft + 4*q);
#pragma unroll
      for (int i = 0; i < 4; ++i) s += acc2[ft][rt][i] * qv[i];
    }
    s += __shfl_xor(s, 16, 64);
    s += __shfl_xor(s, 32, 64);
    p[rt] = s * 0.5773502691896258f;
  }

  // softmax over the 32 rows (row = 16*rt + lm, replicated across q)
  float m = fmaxf(p[0], p[1]);
#pragma unroll
  for (int off = 1; off < 16; off <<= 1) m = fmaxf(m, __shfl_xor(m, off, 64));
  float e0 = __expf(p[0] - m), e1 = __expf(p[1] - m);
  float s = e0 + e1;
#pragma unroll
  for (int off = 1; off < 16; off <<= 1) s += __shfl_xor(s, off, 64);
  const float inv = 1.0f / s;
  float wgt[2] = { e0 * inv, e1 * inv };

  // v pass: consume prefetched slices, then stream the rest (coalesced, once)
  f32x4 acc = (f32x4)(0.f);
#pragma unroll
  for (int s2 = 0; s2 < PF; ++s2) {
    float wk = __shfl(wgt[s2 >> 4], s2 & 15, 64);
    acc += wk * pre[s2];
  }
#pragma unroll
  for (int k = PF; k < 32; ++k) {
    float wk = __shfl(wgt[k >> 4], k & 15, 64);
    f32x4 vv = vp[k * 64];
    acc += wk * vv;
  }
  *(f32x4*)(out + G * 256 + 4*lane) = acc;
}

extern "C" void kernel_launch(void* const* d_in, const int* in_sizes, int n_in,
                              void* d_out, int out_size, void* d_ws, size_t ws_size,
                              hipStream_t stream)
{
  const float* q   = (const float*)d_in[0];
  const float* k   = (const float*)d_in[1];
  const float* v   = (const float*)d_in[2];
  const float* qw0 = (const float*)d_in[3];
  const float* qb0 = (const float*)d_in[4];
  const float* qw1 = (const float*)d_in[5];
  const float* qb1 = (const float*)d_in[6];
  const float* qw2 = (const float*)d_in[7];
  const float* qb2 = (const float*)d_in[8];
  const float* kw0 = (const float*)d_in[9];
  const float* kb0 = (const float*)d_in[10];
  const float* kw1 = (const float*)d_in[11];
  const float* kb1 = (const float*)d_in[12];
  const float* kw2 = (const float*)d_in[13];
  const float* kb2 = (const float*)d_in[14];

  float*    qe = (float*)d_ws;                          // 8 MB
  unsigned* WF = (unsigned*)((char*)d_ws + (8u << 20)); // 40 KB fragments

  prep_kernel<<<2, 256, 0, stream>>>(kw0, kb0, kw1, kw2, qw0, qb0, qw1, qw2, WF);
  qe_mfma_kernel<<<256, 256, 0, stream>>>(q, WF + 5120, qb1, qb2, qe);
  attn_mfma_kernel<<<8192, 256, 0, stream>>>(k, v, WF, kb1, kb2, qe, (float*)d_out);
}

// Round 6
// 190.563 us; speedup vs baseline: 3.5878x; 1.1636x over previous
//
#include <hip/hip_runtime.h>
#include <hip/hip_bf16.h>

typedef __attribute__((ext_vector_type(8))) short bf16x8;
typedef __attribute__((ext_vector_type(4))) float f32x4;

union BF8U { unsigned u[4]; bf16x8 v; };

#define PF_LDS 8   // v-slices DMA'd to LDS per wave (8 KB LDS, 0 VGPR)
#define PF_REG 8   // v-slices prefetched to registers per wave (32 VGPR)

__device__ __forceinline__ unsigned f2bf1(float x){
  unsigned u = __builtin_bit_cast(unsigned, x);
  return (u + 0x7FFFu + ((u >> 16) & 1u)) >> 16;
}
__device__ __forceinline__ unsigned packbf(float a, float b){
  return f2bf1(a) | (f2bf1(b) << 16);
}
__device__ __forceinline__ unsigned cvt2(float a, float b){
  return (unsigned)__bfloat16_as_ushort(__float2bfloat16(a))
       | ((unsigned)__bfloat16_as_ushort(__float2bfloat16(b)) << 16);
}

// Activation tile: 128 rows x 128B, XOR-swizzled within row. Wave-private.
__device__ __forceinline__ int act_addr(int r, int byteInRow){
  return r*128 + (byteInRow ^ ((r & 7) << 4));
}
#define LDS_ACT 16384
#define LDS_V   (LDS_ACT)                 // v region starts after act tile
#define LDS_SZ  (LDS_ACT + 4*PF_LDS*1024) // 16K + 32K = 48K -> 3 blocks/CU

// ---------- prep: pack bf16 weight fragments in exact MFMA arg0 order ------
__global__ __launch_bounds__(256) void prep_kernel(
    const float* __restrict__ kw0, const float* __restrict__ kb0,
    const float* __restrict__ kw1, const float* __restrict__ kw2,
    const float* __restrict__ qw0, const float* __restrict__ qb0,
    const float* __restrict__ qw1, const float* __restrict__ qw2,
    unsigned* __restrict__ WF)
{
  const int t = threadIdx.x;
  const int path = blockIdx.x;
  const float* w0 = path ? qw0 : kw0;
  const float* b0 = path ? qb0 : kb0;
  const float* w1 = path ? qw1 : kw1;
  const float* w2 = path ? qw2 : kw2;
  unsigned* out = WF + path * 5120;
#pragma unroll
  for (int u = 0; u < 4; ++u) {
    int s2 = t + 256*u;
    int j2 = s2 & 3, l = (s2 >> 2) & 63, ct = s2 >> 8;
    int feat = 16*ct + (l & 15);
    int k0 = 8*(l >> 4) + 2*j2;
    float a = (k0   < 3) ? w0[feat*3 + k0]   : (k0   == 3 ? b0[feat] : 0.f);
    float b = (k0+1 < 3) ? w0[feat*3 + k0+1] : (k0+1 == 3 ? b0[feat] : 0.f);
    out[s2] = packbf(a, b);
  }
#pragma unroll
  for (int u = 0; u < 8; ++u) {
    int s2 = t + 256*u;
    int j2 = s2 & 3, l = (s2 >> 2) & 63, ctks = s2 >> 8;
    int feat = 16*(ctks & 3) + (l & 15);
    int k = 32*(ctks >> 2) + 8*(l >> 4) + 2*j2;
    out[1024 + s2] = packbf(w1[feat*64 + k], w1[feat*64 + k + 1]);
    out[3072 + s2] = packbf(w2[feat*64 + k], w2[feat*64 + k + 1]);
  }
}

// ---------- 3-layer MLP on 32 rows/wave from pre-loaded x, no barriers -----
__device__ __forceinline__ void mlp3(char* lds, int t,
    const float xv[2][3],
    const unsigned* __restrict__ WF,
    const float* __restrict__ b1, const float* __restrict__ b2,
    f32x4 acc2[4][2])
{
  const int lane = t & 63;
  const int q = lane >> 4, lm = lane & 15;
  const int wbase = (t >> 6) * 32;

  bf16x8 a0[2];
#pragma unroll
  for (int rt = 0; rt < 2; ++rt) {
    BF8U u;
    u.u[0] = (q == 0) ? cvt2(xv[rt][0], xv[rt][1]) : 0u;
    u.u[1] = (q == 0) ? cvt2(xv[rt][2], 1.0f)      : 0u;
    u.u[2] = 0u; u.u[3] = 0u;
    a0[rt] = u.v;
  }

  f32x4 h[4][2];

  { // layer 0 (K=32, bias folded into W0')
    bf16x8 wf[4];
#pragma unroll
    for (int ft = 0; ft < 4; ++ft)
      wf[ft] = *(const bf16x8*)(WF + ft*256 + lane*4);
#pragma unroll
    for (int ft = 0; ft < 4; ++ft)
#pragma unroll
      for (int rt = 0; rt < 2; ++rt) {
        h[ft][rt] = (f32x4)(0.f);
        h[ft][rt] = __builtin_amdgcn_mfma_f32_16x16x32_bf16(wf[ft], a0[rt], h[ft][rt], 0, 0, 0);
      }
#pragma unroll
    for (int ft = 0; ft < 4; ++ft)
#pragma unroll
      for (int rt = 0; rt < 2; ++rt) {
        int rr = wbase + 16*rt + lm;
        f32x4 vv = h[ft][rt];
        uint2 wp;
        wp.x = cvt2(fmaxf(vv[0],0.f), fmaxf(vv[1],0.f));
        wp.y = cvt2(fmaxf(vv[2],0.f), fmaxf(vv[3],0.f));
        *(uint2*)(lds + act_addr(rr, (16*ft + 4*q)*2)) = wp;
      }
  }

  { // layer 1 (K=64, bias, relu)
    bf16x8 a1[2][2];
#pragma unroll
    for (int rt = 0; rt < 2; ++rt)
#pragma unroll
      for (int ks = 0; ks < 2; ++ks)
        a1[rt][ks] = *(const bf16x8*)(lds + act_addr(wbase + 16*rt + lm, 64*ks + 16*q));
    bf16x8 wf[8];
#pragma unroll
    for (int c = 0; c < 8; ++c)
      wf[c] = *(const bf16x8*)(WF + 1024 + c*256 + lane*4);
#pragma unroll
    for (int ft = 0; ft < 4; ++ft)
#pragma unroll
      for (int rt = 0; rt < 2; ++rt) {
        h[ft][rt] = (f32x4)(0.f);
        h[ft][rt] = __builtin_amdgcn_mfma_f32_16x16x32_bf16(wf[ft],   a1[rt][0], h[ft][rt], 0, 0, 0);
        h[ft][rt] = __builtin_amdgcn_mfma_f32_16x16x32_bf16(wf[4+ft], a1[rt][1], h[ft][rt], 0, 0, 0);
      }
#pragma unroll
    for (int ft = 0; ft < 4; ++ft) {
      f32x4 b1f = *(const f32x4*)(b1 + 16*ft + 4*q);
#pragma unroll
      for (int rt = 0; rt < 2; ++rt) {
        int rr = wbase + 16*rt + lm;
        f32x4 vv = h[ft][rt];
        uint2 wp;
        wp.x = cvt2(fmaxf(vv[0]+b1f[0],0.f), fmaxf(vv[1]+b1f[1],0.f));
        wp.y = cvt2(fmaxf(vv[2]+b1f[2],0.f), fmaxf(vv[3]+b1f[3],0.f));
        *(uint2*)(lds + act_addr(rr, (16*ft + 4*q)*2)) = wp;
      }
    }
  }

  { // layer 2 (K=64, bias, linear)
    bf16x8 a2[2][2];
#pragma unroll
    for (int rt = 0; rt < 2; ++rt)
#pragma unroll
      for (int ks = 0; ks < 2; ++ks)
        a2[rt][ks] = *(const bf16x8*)(lds + act_addr(wbase + 16*rt + lm, 64*ks + 16*q));
    bf16x8 wf[8];
#pragma unroll
    for (int c = 0; c < 8; ++c)
      wf[c] = *(const bf16x8*)(WF + 3072 + c*256 + lane*4);
#pragma unroll
    for (int ft = 0; ft < 4; ++ft)
#pragma unroll
      for (int rt = 0; rt < 2; ++rt) {
        acc2[ft][rt] = (f32x4)(0.f);
        acc2[ft][rt] = __builtin_amdgcn_mfma_f32_16x16x32_bf16(wf[ft],   a2[rt][0], acc2[ft][rt], 0, 0, 0);
        acc2[ft][rt] = __builtin_amdgcn_mfma_f32_16x16x32_bf16(wf[4+ft], a2[rt][1], acc2[ft][rt], 0, 0, 0);
      }
#pragma unroll
    for (int ft = 0; ft < 4; ++ft) {
      f32x4 b2f = *(const f32x4*)(b2 + 16*ft + 4*q);
#pragma unroll
      for (int rt = 0; rt < 2; ++rt)
#pragma unroll
        for (int i = 0; i < 4; ++i) acc2[ft][rt][i] += b2f[i];
    }
  }
}

// -------- q-path: MLP -> qe (fp32) --------
__global__ __launch_bounds__(256, 3) void qe_mfma_kernel(
    const float* __restrict__ qin, const unsigned* __restrict__ WF,
    const float* __restrict__ b1, const float* __restrict__ b2,
    float* __restrict__ qeout)
{
  __shared__ __align__(16) char lds[LDS_ACT];
  const int t = threadIdx.x;
  const int lane = t & 63, wv = t >> 6, q = lane >> 4, lm = lane & 15;
  const long rowbase = (long)blockIdx.x * 128;
  const int wbase = wv * 32;
  float xv[2][3];
#pragma unroll
  for (int rt = 0; rt < 2; ++rt) {
    const float* xr = qin + (rowbase + wbase + 16*rt + lm) * 3;
    xv[rt][0] = xr[0]; xv[rt][1] = xr[1]; xv[rt][2] = xr[2];
  }
  f32x4 acc2[4][2];
  mlp3(lds, t, xv, WF, b1, b2, acc2);
#pragma unroll
  for (int ft = 0; ft < 4; ++ft)
#pragma unroll
    for (int rt = 0; rt < 2; ++rt) {
      long grow = rowbase + wbase + 16*rt + lm;
      *(f32x4*)(qeout + grow*64 + 16*ft + 4*q) = acc2[ft][rt];
    }
}

// -------- k-path: MLP -> logits -> softmax -> weighted v-sum --------
// One wave per group. v prefetched 16-deep (8 LDS-DMA + 8 reg) under the MLP.
__global__ __launch_bounds__(256, 3) void attn_mfma_kernel(
    const float* __restrict__ kin, const float* __restrict__ v,
    const unsigned* __restrict__ WF,
    const float* __restrict__ b1, const float* __restrict__ b2,
    const float* __restrict__ qe, float* __restrict__ out)
{
  __shared__ __align__(16) char lds[LDS_SZ];
  const int t = threadIdx.x;
  const int lane = t & 63, wv = t >> 6, q = lane >> 4, lm = lane & 15;
  const long rowbase = (long)blockIdx.x * 128;
  const int wbase = wv * 32;
  const long G = (long)blockIdx.x * 4 + wv;   // this wave's group

  // (1) k-row loads (oldest in VMEM FIFO -> MLP waits only these)
  float xv[2][3];
#pragma unroll
  for (int rt = 0; rt < 2; ++rt) {
    const float* xr = kin + (rowbase + wbase + 16*rt + lm) * 3;
    xv[rt][0] = xr[0]; xv[rt][1] = xr[1]; xv[rt][2] = xr[2];
  }

  // (2) qe preload (needed only post-MLP; removes HBM-miss from serial phase)
  const float* qp = qe + G * 64;
  f32x4 qv[4];
#pragma unroll
  for (int ft = 0; ft < 4; ++ft) qv[ft] = *(const f32x4*)(qp + 16*ft + 4*q);
  __builtin_amdgcn_sched_barrier(0);

  // (3) v-prefetch, 16-deep: slices 0..7 DMA'd to LDS (no VGPR), 8..15 to regs
  const char* gv = (const char*)(v + G * 8192);
  char* vlds = lds + LDS_V + wv * (PF_LDS * 1024);
#pragma unroll
  for (int s = 0; s < PF_LDS; ++s)
    __builtin_amdgcn_global_load_lds(
        (const __attribute__((address_space(1))) void*)(gv + s*1024 + lane*16),
        (__attribute__((address_space(3))) void*)(vlds + s*1024),
        16, 0, 0);
  const f32x4* vp = (const f32x4*)(v + G * 8192) + lane;
  f32x4 pre[PF_REG];
#pragma unroll
  for (int s = 0; s < PF_REG; ++s)
    pre[s] = __builtin_nontemporal_load(vp + (PF_LDS + s) * 64);
  __builtin_amdgcn_sched_barrier(0);

  // (4) MLP (VMEM-silent except L2-hit weight fragments)
  f32x4 acc2[4][2];
  mlp3(lds, t, xv, WF, b1, b2, acc2);

  // (5) logit = (ke . qe(G)) / sqrt(3); reduce over q groups
  float p[2];
#pragma unroll
  for (int rt = 0; rt < 2; ++rt) {
    float s = 0.f;
#pragma unroll
    for (int ft = 0; ft < 4; ++ft)
#pragma unroll
      for (int i = 0; i < 4; ++i) s += acc2[ft][rt][i] * qv[ft][i];
    s += __shfl_xor(s, 16, 64);
    s += __shfl_xor(s, 32, 64);
    p[rt] = s * 0.5773502691896258f;
  }

  // (6) softmax over the 32 rows (row = 16*rt + lm, replicated across q)
  float m = fmaxf(p[0], p[1]);
#pragma unroll
  for (int off = 1; off < 16; off <<= 1) m = fmaxf(m, __shfl_xor(m, off, 64));
  float e0 = __expf(p[0] - m), e1 = __expf(p[1] - m);
  float s = e0 + e1;
#pragma unroll
  for (int off = 1; off < 16; off <<= 1) s += __shfl_xor(s, off, 64);
  const float inv = 1.0f / s;
  float wgt[2] = { e0 * inv, e1 * inv };

  // (7) v pass: LDS slices 0..7, reg slices 8..15, stream 16..31 (NT)
  f32x4 acc = (f32x4)(0.f);
  asm volatile("s_waitcnt vmcnt(0)" ::: "memory");  // global_load_lds retired
#pragma unroll
  for (int s2 = 0; s2 < PF_LDS; ++s2) {
    float wk = __shfl(wgt[0], s2, 64);
    f32x4 vv = *(const f32x4*)(vlds + s2*1024 + lane*16);
    acc += wk * vv;
  }
#pragma unroll
  for (int s2 = 0; s2 < PF_REG; ++s2) {
    int k = PF_LDS + s2;
    float wk = __shfl(wgt[k >> 4], k & 15, 64);
    acc += wk * pre[s2];
  }
#pragma unroll
  for (int k = PF_LDS + PF_REG; k < 32; ++k) {
    float wk = __shfl(wgt[k >> 4], k & 15, 64);
    f32x4 vv = __builtin_nontemporal_load(vp + k * 64);
    acc += wk * vv;
  }
  __builtin_nontemporal_store(acc, (f32x4*)(out + G * 256 + 4*lane));
}

extern "C" void kernel_launch(void* const* d_in, const int* in_sizes, int n_in,
                              void* d_out, int out_size, void* d_ws, size_t ws_size,
                              hipStream_t stream)
{
  const float* q   = (const float*)d_in[0];
  const float* k   = (const float*)d_in[1];
  const float* v   = (const float*)d_in[2];
  const float* qw0 = (const float*)d_in[3];
  const float* qb0 = (const float*)d_in[4];
  const float* qw1 = (const float*)d_in[5];
  const float* qb1 = (const float*)d_in[6];
  const float* qw2 = (const float*)d_in[7];
  const float* qb2 = (const float*)d_in[8];
  const float* kw0 = (const float*)d_in[9];
  const float* kb0 = (const float*)d_in[10];
  const float* kw1 = (const float*)d_in[11];
  const float* kb1 = (const float*)d_in[12];
  const float* kw2 = (const float*)d_in[13];
  const float* kb2 = (const float*)d_in[14];

  float*    qe = (float*)d_ws;                          // 8 MB
  unsigned* WF = (unsigned*)((char*)d_ws + (8u << 20)); // 40 KB fragments

  prep_kernel<<<2, 256, 0, stream>>>(kw0, kb0, kw1, kw2, qw0, qb0, qw1, qw2, WF);
  qe_mfma_kernel<<<256, 256, 0, stream>>>(q, WF + 5120, qb1, qb2, qe);
  attn_mfma_kernel<<<8192, 256, 0, stream>>>(k, v, WF, kb1, kb2, qe, (float*)d_out);
}